// Round 2
// baseline (76.437 us; speedup 1.0000x reference)
//
#include <hip/hip_runtime.h>

// GraphConv2d (EdgeConv): out[b,o,n] = max_k relu( W·[x_n, x_m-x_n] + b )
// Factorized: U[b,n,o] = (W1-W2)·x_n + b ; V[b,m,o] = W2·x_m
//             out = relu(U + max_k V[m_k])   (relu monotone, U k-invariant)
// B=2, C=64, N=65536, K=16, OUT=64.

using u32 = unsigned int;
using u16 = unsigned short;
typedef __fp16 h2 __attribute__((ext_vector_type(2)));  // matches cvt_pkrtz/fdot2

#define NN 65536
#define NTILES 1024  // N/64

static __device__ __forceinline__ u32 pack_bf16(float a, float b) {
  u32 ua = __builtin_bit_cast(u32, a);
  u32 ub = __builtin_bit_cast(u32, b);
  ua = (ua + 0x7fffu + ((ua >> 16) & 1u)) >> 16;  // RNE
  ub = (ub + 0x7fffu + ((ub >> 16) & 1u)) >> 16;
  return ua | (ub << 16);
}
static __device__ __forceinline__ float bf16f(u16 v) {
  u32 u = ((u32)v) << 16;
  return __builtin_bit_cast(float, u);
}
static __device__ __forceinline__ float dot2(h2 a, h2 b, float c) {
#if defined(__has_builtin)
#if __has_builtin(__builtin_amdgcn_fdot2)
  return __builtin_amdgcn_fdot2(a, b, c, false);
#else
  return c + (float)a[0] * (float)b[0] + (float)a[1] * (float)b[1];
#endif
#else
  return c + (float)a[0] * (float)b[0] + (float)a[1] * (float)b[1];
#endif
}

// ---- kernel 0: pack W (f32 [64][128]) into f16 pairs, layout Wh[h][c2][o] ----
__global__ __launch_bounds__(256) void prep_w(const float* __restrict__ W,
                                              u32* __restrict__ Wh) {
  int t = threadIdx.x;
#pragma unroll
  for (int r = 0; r < 16; ++r) {
    int id = r * 256 + t;        // id = (h*32 + c2)*64 + o
    int o = id & 63;
    int c2 = (id >> 6) & 31;
    int h = id >> 11;
    float f0 = W[o * 128 + h * 64 + 2 * c2];
    float f1 = W[o * 128 + h * 64 + 2 * c2 + 1];
    h2 p = __builtin_amdgcn_cvt_pkrtz(f0, f1);
    Wh[id] = __builtin_bit_cast(u32, p);
  }
}

// ---- kernel 1: U[b,n,o], V[b,n,o] (bf16, node-major) via dual dot2 GEMM ----
__global__ __launch_bounds__(256) void k1(const float* __restrict__ x,
                                          const float* __restrict__ bias,
                                          const u32* __restrict__ Wh,
                                          u16* __restrict__ Ubf,
                                          u16* __restrict__ Vbf) {
  __shared__ u32 feat2[32][64];   // packed f16 pair (c,c+1) per node j
  __shared__ u32 trans[64][33];   // transpose staging (padded, conflict-free)

  int t = threadIdx.x;
  int j = t & 63;                 // node within tile
  int q = t >> 6;                 // wave id 0..3
  int b = blockIdx.x >> 10;
  int n0 = (blockIdx.x & 1023) << 6;

  // stage x tile -> LDS as packed f16 pairs (coalesced 256B rows)
#pragma unroll
  for (int r = 0; r < 8; ++r) {
    int c2 = r * 4 + q;
    size_t base = ((size_t)(b * 64 + 2 * c2)) * NN + n0 + j;
    float f0 = x[base];
    float f1 = x[base + NN];
    h2 p = __builtin_amdgcn_cvt_pkrtz(f0, f1);
    feat2[c2][j] = __builtin_bit_cast(u32, p);
  }
  __syncthreads();

  int og = __builtin_amdgcn_readfirstlane(q);  // wave-uniform o-group
  float accA[16], accV[16];
#pragma unroll
  for (int oo = 0; oo < 16; ++oo) { accA[oo] = 0.f; accV[oo] = 0.f; }

#pragma unroll 4
  for (int c2 = 0; c2 < 32; ++c2) {
    h2 f2 = __builtin_bit_cast(h2, feat2[c2][j]);
#pragma unroll
    for (int oo = 0; oo < 16; ++oo) {
      // wave-uniform indices -> scalar loads (L2-hot, 16KB table)
      h2 w1 = __builtin_bit_cast(h2, Wh[c2 * 64 + og * 16 + oo]);
      h2 w2 = __builtin_bit_cast(h2, Wh[(32 + c2) * 64 + og * 16 + oo]);
      accA[oo] = dot2(w1, f2, accA[oo]);  // W1·x
      accV[oo] = dot2(w2, f2, accV[oo]);  // W2·x
    }
  }

  // ---- U = accA - accV + bias : transpose to node-major, write bf16 ----
#pragma unroll
  for (int oo2 = 0; oo2 < 8; ++oo2) {
    float u0 = accA[2 * oo2] - accV[2 * oo2] + bias[og * 16 + 2 * oo2];
    float u1 = accA[2 * oo2 + 1] - accV[2 * oo2 + 1] + bias[og * 16 + 2 * oo2 + 1];
    trans[j][og * 8 + oo2] = pack_bf16(u0, u1);
  }
  __syncthreads();
  {
    u32* Up = (u32*)Ubf;
#pragma unroll
    for (int r = 0; r < 8; ++r) {
      int nn = r * 8 + (t >> 5);
      int o2 = t & 31;
      Up[((size_t)(b * NN + n0 + nn)) * 32 + o2] = trans[nn][o2];
    }
  }
  __syncthreads();

  // ---- V = accV ----
#pragma unroll
  for (int oo2 = 0; oo2 < 8; ++oo2) {
    trans[j][og * 8 + oo2] = pack_bf16(accV[2 * oo2], accV[2 * oo2 + 1]);
  }
  __syncthreads();
  {
    u32* Vp = (u32*)Vbf;
#pragma unroll
    for (int r = 0; r < 8; ++r) {
      int nn = r * 8 + (t >> 5);
      int o2 = t & 31;
      Vp[((size_t)(b * NN + n0 + nn)) * 32 + o2] = trans[nn][o2];
    }
  }
}

// ---- kernel 2: gather + max + relu, coalesced output via LDS transpose ----
__global__ __launch_bounds__(256) void k2(const int* __restrict__ eidx,
                                          const u16* __restrict__ Ubf,
                                          const u16* __restrict__ Vbf,
                                          float* __restrict__ out) {
  __shared__ float tile[64][65];  // [o][node], padded row -> conflict-free

  int t = threadIdx.x;
  int lane = t & 63;              // output channel o
  int b = blockIdx.x >> 10;
  int n0 = (blockIdx.x & 1023) << 6;
  int w = __builtin_amdgcn_readfirstlane(t >> 6);

  size_t vb = ((size_t)b) * NN * 64 + lane;

  for (int s = 0; s < 16; ++s) {
    int nl = (w << 4) + s;
    int n = n0 + nl;
    const int* ip = eidx + ((size_t)(b * NN + n)) * 16;  // edge_index[0][b][n][:]
    int4 i0 = ((const int4*)ip)[0];
    int4 i1 = ((const int4*)ip)[1];
    int4 i2 = ((const int4*)ip)[2];
    int4 i3 = ((const int4*)ip)[3];

    // 16 gathers, each 128B contiguous across the wave (bf16 x 64 lanes)
    u16 g0 = Vbf[vb + (size_t)i0.x * 64];
    u16 g1 = Vbf[vb + (size_t)i0.y * 64];
    u16 g2 = Vbf[vb + (size_t)i0.z * 64];
    u16 g3 = Vbf[vb + (size_t)i0.w * 64];
    u16 g4 = Vbf[vb + (size_t)i1.x * 64];
    u16 g5 = Vbf[vb + (size_t)i1.y * 64];
    u16 g6 = Vbf[vb + (size_t)i1.z * 64];
    u16 g7 = Vbf[vb + (size_t)i1.w * 64];
    u16 g8 = Vbf[vb + (size_t)i2.x * 64];
    u16 g9 = Vbf[vb + (size_t)i2.y * 64];
    u16 ga = Vbf[vb + (size_t)i2.z * 64];
    u16 gb = Vbf[vb + (size_t)i2.w * 64];
    u16 gc = Vbf[vb + (size_t)i3.x * 64];
    u16 gd = Vbf[vb + (size_t)i3.y * 64];
    u16 ge = Vbf[vb + (size_t)i3.z * 64];
    u16 gf = Vbf[vb + (size_t)i3.w * 64];

    float u = bf16f(Ubf[((size_t)(b * NN + n)) * 64 + lane]);

    float m01 = fmaxf(bf16f(g0), bf16f(g1));
    float m23 = fmaxf(bf16f(g2), bf16f(g3));
    float m45 = fmaxf(bf16f(g4), bf16f(g5));
    float m67 = fmaxf(bf16f(g6), bf16f(g7));
    float m89 = fmaxf(bf16f(g8), bf16f(g9));
    float mab = fmaxf(bf16f(ga), bf16f(gb));
    float mcd = fmaxf(bf16f(gc), bf16f(gd));
    float mef = fmaxf(bf16f(ge), bf16f(gf));
    float m = fmaxf(fmaxf(fmaxf(m01, m23), fmaxf(m45, m67)),
                    fmaxf(fmaxf(m89, mab), fmaxf(mcd, mef)));

    tile[lane][nl] = fmaxf(u + m, 0.0f);  // relu(U + max_k V)
  }
  __syncthreads();

#pragma unroll
  for (int r = 0; r < 16; ++r) {
    int o = (r << 2) + (t >> 6);
    int jj = t & 63;
    out[((size_t)(b * 64 + o)) * NN + n0 + jj] = tile[o][jj];
  }
}

extern "C" void kernel_launch(void* const* d_in, const int* in_sizes, int n_in,
                              void* d_out, int out_size, void* d_ws, size_t ws_size,
                              hipStream_t stream) {
  const float* x = (const float*)d_in[0];
  const int* eidx = (const int*)d_in[1];   // edge_index (int), we use [0] half
  const float* W = (const float*)d_in[2];  // [64][128]
  const float* bias = (const float*)d_in[3];

  // workspace layout: U bf16 (16 MB) | V bf16 (16 MB) | Wh packed f16 (16 KB)
  u16* Ubf = (u16*)d_ws;
  u16* Vbf = Ubf + (size_t)2 * NN * 64;
  u32* Wh = (u32*)((char*)d_ws + (size_t)2 * 2 * NN * 64 * sizeof(u16));

  prep_w<<<1, 256, 0, stream>>>(W, Wh);
  k1<<<2 * NTILES, 256, 0, stream>>>(x, bias, Wh, Ubf, Vbf);
  k2<<<2 * NTILES, 256, 0, stream>>>(eidx, Ubf, Vbf, (float*)d_out);
}

// Round 4
// 59.967 us; speedup vs baseline: 1.2746x; 1.2746x over previous
//
#include <hip/hip_runtime.h>

// GraphConv2d (EdgeConv): out[b,o,n] = max_k relu( W·[x_n, x_m-x_n] + b )
// Factorized: U[b,n,o] = (W1-W2)·x_n + b ; V[b,m,o] = W2·x_m
//             out = relu(U + max_k V[m_k])   (relu monotone, U k-invariant)
// B=2, C=64, N=65536, K=16, OUT=64.

using u32 = unsigned int;
using u16 = unsigned short;
typedef short short8 __attribute__((ext_vector_type(8)));
typedef float f32x4 __attribute__((ext_vector_type(4)));
typedef int i32x4 __attribute__((ext_vector_type(4)));

#define NN 65536

static __device__ __forceinline__ u16 bf16r(float a) {
  u32 u = __builtin_bit_cast(u32, a);
  return (u16)((u + 0x7fffu + ((u >> 16) & 1u)) >> 16);  // RNE
}
static __device__ __forceinline__ u32 pack_bf16(float a, float b) {
  return (u32)bf16r(a) | ((u32)bf16r(b) << 16);
}
static __device__ __forceinline__ float bf16f(u16 v) {
  u32 u = ((u32)v) << 16;
  return __builtin_bit_cast(float, u);
}

// ---- kernel 0: Wcat[128][64] bf16: rows 0..63 = (W1-W2), 64..127 = W2 ----
__global__ __launch_bounds__(256) void prep_w(const float* __restrict__ W,
                                              u32* __restrict__ Wcat) {
  int id = blockIdx.x * 256 + threadIdx.x;  // 0..4095 (grid=16)
  int o = id >> 5, c2 = id & 31;
  float f0, f1;
  if (o < 64) {
    f0 = W[o * 128 + 2 * c2]     - W[o * 128 + 64 + 2 * c2];
    f1 = W[o * 128 + 2 * c2 + 1] - W[o * 128 + 64 + 2 * c2 + 1];
  } else {
    int om = o - 64;
    f0 = W[om * 128 + 64 + 2 * c2];
    f1 = W[om * 128 + 64 + 2 * c2 + 1];
  }
  Wcat[id] = pack_bf16(f0, f1);
}

// ---- kernel 1: U,V (bf16 node-major) via MFMA GEMM  C[64n x 128o] ----
// A = x tile [64 nodes][64 ch] bf16 ; B^T = Wcat [128 outs][64 ch] bf16
__global__ __launch_bounds__(256, 4) void k1(const float* __restrict__ x,
                                             const float* __restrict__ bias,
                                             const u32* __restrict__ Wcat,
                                             u16* __restrict__ Ubf,
                                             u16* __restrict__ Vbf) {
  __shared__ __align__(16) char smem[26880];  // Wb(18432)+Xa(8448); reused: TR(17408)
  u32* Wb = (u32*)smem;            // [128][36] u32  (row = 72 bf16, padded)
  u32* Xa = (u32*)(smem + 18432);  // [64][33] u32   (row = 66 bf16, padded)

  int t = threadIdx.x;
  int l = t & 63;   // lane
  int w = t >> 6;   // wave 0..3
  int b = blockIdx.x >> 10;
  int n0 = (blockIdx.x & 1023) << 6;

  // stage Wcat -> LDS (padded rows, conflict-free b128 reads later)
#pragma unroll
  for (int i = 0; i < 16; ++i) {
    int id = i * 256 + t;  // o = id>>5, c2 = id&31
    Wb[(id >> 5) * 36 + (id & 31)] = Wcat[id];
  }
  // stage x tile -> LDS bf16 pairs: Xa[node][ch], coalesced 256B reads
#pragma unroll
  for (int r = 0; r < 8; ++r) {
    int c2 = r * 4 + w;
    size_t base = ((size_t)(b * 64 + 2 * c2)) * NN + n0 + l;
    Xa[l * 33 + c2] = pack_bf16(x[base], x[base + NN]);
  }
  __syncthreads();

  f32x4 acc[8];
#pragma unroll
  for (int f = 0; f < 8; ++f) acc[f] = {0.f, 0.f, 0.f, 0.f};

  // wave w owns nodes 16w..16w+15 (C rows), all 128 outs (8 col-frags)
#pragma unroll
  for (int kb = 0; kb < 2; ++kb) {  // K = 64 = 2 x 32
    int ar = (16 * w + (l & 15)) * 33 + kb * 16 + 4 * (l >> 4);
    i32x4 av = {(int)Xa[ar], (int)Xa[ar + 1], (int)Xa[ar + 2], (int)Xa[ar + 3]};
    short8 a = __builtin_bit_cast(short8, av);
#pragma unroll
    for (int f = 0; f < 8; ++f) {
      i32x4 bv = *(const i32x4*)(Wb + (16 * f + (l & 15)) * 36 + kb * 16 + 4 * (l >> 4));
      short8 bb = __builtin_bit_cast(short8, bv);
      acc[f] = __builtin_amdgcn_mfma_f32_16x16x32_bf16(a, bb, acc[f], 0, 0, 0);
    }
  }

  float bs[4];
#pragma unroll
  for (int f = 0; f < 4; ++f) bs[f] = bias[16 * f + (l & 15)];

  __syncthreads();  // all waves done with Wb/Xa before reuse
  u16* TR16 = (u16*)smem;  // [64 nodes][136 u16]  (U: 0..63 | V: 64..127, pad 8)
#pragma unroll
  for (int f = 0; f < 4; ++f) {
#pragma unroll
    for (int r = 0; r < 4; ++r) {
      int node = 16 * w + 4 * (l >> 4) + r;  // D row = (lane>>4)*4 + reg
      int o = 16 * f + (l & 15);             // D col = lane&15
      // Wcat rows 0..63 are ALREADY (W1-W2): U = acc[f] + bias. (r3 bug: double-subtracted V)
      float uval = acc[f][r] + bs[f];
      float vval = acc[f + 4][r];
      TR16[node * 136 + o] = bf16r(uval);
      TR16[node * 136 + 64 + o] = bf16r(vval);
    }
  }
  __syncthreads();

  // coalesced node-major writeback: U and V rows are 32 u32 each
  u32* TR32 = (u32*)smem;
  u32* Up = (u32*)Ubf;
  u32* Vp = (u32*)Vbf;
  int o2 = t & 63;
#pragma unroll
  for (int i = 0; i < 16; ++i) {
    int n = i * 4 + w;
    u32 v = TR32[n * 68 + o2];
    size_t nb = (size_t)(b * NN + n0 + n);
    if (o2 < 32) Up[nb * 32 + o2] = v;
    else         Vp[nb * 32 + (o2 - 32)] = v;
  }
}

// ---- kernel 2: gather + max + relu; idx pre-hoisted to VGPRs ----
__global__ __launch_bounds__(256, 4) void k2(const int* __restrict__ eidx,
                                             const u16* __restrict__ Ubf,
                                             const u16* __restrict__ Vbf,
                                             float* __restrict__ out) {
  __shared__ float tile[64][65];  // [o][node], padded

  int t = threadIdx.x;
  int l = t & 63;   // output channel o
  int w = t >> 6;   // wave: nodes w*16..w*16+15
  int b = blockIdx.x >> 10;
  int n0 = (blockIdx.x & 1023) << 6;

  // wave's 16 nodes x 16 idx = 256 ints: one int4 per lane, fully coalesced.
  // lane l holds idx quad: chunk[4l..4l+3]; node s's k-th idx = chunk[16s+k]
  const int4* e4 = (const int4*)(eidx + ((size_t)(b * NN) + n0 + w * 16) * 16);
  int4 mi = e4[l];

  const u16* Vb = Vbf + ((size_t)b) * NN * 64 + l;
  const u16* Ub = Ubf + ((size_t)(b * NN) + n0 + w * 16) * 64 + l;

#pragma unroll
  for (int s = 0; s < 16; ++s) {
    int lb = 4 * s;
    int e0 = __builtin_amdgcn_readlane(mi.x, lb);
    int e1 = __builtin_amdgcn_readlane(mi.y, lb);
    int e2 = __builtin_amdgcn_readlane(mi.z, lb);
    int e3 = __builtin_amdgcn_readlane(mi.w, lb);
    int e4_ = __builtin_amdgcn_readlane(mi.x, lb + 1);
    int e5 = __builtin_amdgcn_readlane(mi.y, lb + 1);
    int e6 = __builtin_amdgcn_readlane(mi.z, lb + 1);
    int e7 = __builtin_amdgcn_readlane(mi.w, lb + 1);
    int e8 = __builtin_amdgcn_readlane(mi.x, lb + 2);
    int e9 = __builtin_amdgcn_readlane(mi.y, lb + 2);
    int ea = __builtin_amdgcn_readlane(mi.z, lb + 2);
    int eb = __builtin_amdgcn_readlane(mi.w, lb + 2);
    int ec = __builtin_amdgcn_readlane(mi.x, lb + 3);
    int ed = __builtin_amdgcn_readlane(mi.y, lb + 3);
    int ee = __builtin_amdgcn_readlane(mi.z, lb + 3);
    int ef = __builtin_amdgcn_readlane(mi.w, lb + 3);

    // 16 independent gathers, each 128B coalesced across the wave
    float g0 = bf16f(Vb[(size_t)e0 * 64]);
    float g1 = bf16f(Vb[(size_t)e1 * 64]);
    float g2 = bf16f(Vb[(size_t)e2 * 64]);
    float g3 = bf16f(Vb[(size_t)e3 * 64]);
    float g4 = bf16f(Vb[(size_t)e4_ * 64]);
    float g5 = bf16f(Vb[(size_t)e5 * 64]);
    float g6 = bf16f(Vb[(size_t)e6 * 64]);
    float g7 = bf16f(Vb[(size_t)e7 * 64]);
    float g8 = bf16f(Vb[(size_t)e8 * 64]);
    float g9 = bf16f(Vb[(size_t)e9 * 64]);
    float ga = bf16f(Vb[(size_t)ea * 64]);
    float gb = bf16f(Vb[(size_t)eb * 64]);
    float gc = bf16f(Vb[(size_t)ec * 64]);
    float gd = bf16f(Vb[(size_t)ed * 64]);
    float ge = bf16f(Vb[(size_t)ee * 64]);
    float gf = bf16f(Vb[(size_t)ef * 64]);

    float u = bf16f(Ub[(size_t)s * 64]);  // imm-offset load

    float m = fmaxf(fmaxf(fmaxf(fmaxf(g0, g1), fmaxf(g2, g3)),
                          fmaxf(fmaxf(g4, g5), fmaxf(g6, g7))),
                    fmaxf(fmaxf(fmaxf(g8, g9), fmaxf(ga, gb)),
                          fmaxf(fmaxf(gc, gd), fmaxf(ge, gf))));

    tile[l][w * 16 + s] = fmaxf(u + m, 0.0f);
  }
  __syncthreads();

#pragma unroll
  for (int r = 0; r < 16; ++r) {
    int o = (r << 2) + (t >> 6);
    int jj = t & 63;
    out[((size_t)(b * 64 + o)) * NN + n0 + jj] = tile[o][jj];
  }
}

extern "C" void kernel_launch(void* const* d_in, const int* in_sizes, int n_in,
                              void* d_out, int out_size, void* d_ws, size_t ws_size,
                              hipStream_t stream) {
  const float* x = (const float*)d_in[0];
  const int* eidx = (const int*)d_in[1];
  const float* W = (const float*)d_in[2];
  const float* bias = (const float*)d_in[3];

  // ws: U bf16 (16 MB) | V bf16 (16 MB) | Wcat bf16 (16 KB)
  u16* Ubf = (u16*)d_ws;
  u16* Vbf = Ubf + (size_t)2 * NN * 64;
  u32* Wcat = (u32*)((char*)d_ws + (size_t)2 * 2 * NN * 64 * sizeof(u16));

  prep_w<<<16, 256, 0, stream>>>(W, Wcat);
  k1<<<2 * 1024, 256, 0, stream>>>(x, bias, Wcat, Ubf, Vbf);
  k2<<<2 * 1024, 256, 0, stream>>>(eidx, Ubf, Vbf, (float*)d_out);
}